// Round 9
// baseline (1620.882 us; speedup 1.0000x reference)
//
#include <hip/hip_runtime.h>

#define DIM 384
#define HEADS 12
#define HD 32
#define NTOK 49
#define NWIN 4096
#define MTOT (NWIN*NTOK)   // 200704

typedef __attribute__((ext_vector_type(8))) __bf16 bf16x8;
typedef __attribute__((ext_vector_type(4))) __bf16 bf16x4;
typedef __attribute__((ext_vector_type(4))) float f32x4;

static __device__ __forceinline__ f32x4 mfma16(bf16x8 a, bf16x8 b, f32x4 c) {
  return __builtin_amdgcn_mfma_f32_16x16x32_bf16(a, b, c, 0, 0, 0);
}

static __device__ __forceinline__ bf16x4 cvt4(float4 v) {
  bf16x4 t;
  t[0]=(__bf16)v.x; t[1]=(__bf16)v.y; t[2]=(__bf16)v.z; t[3]=(__bf16)v.w;
  return t;
}

// ---------------- prep: weights -> bf16, bias table expand ----------------
__global__ void k_prep(const float* __restrict__ qw, const float* __restrict__ kvw,
                       const float* __restrict__ pw, const float* __restrict__ rel_table,
                       const int* __restrict__ rel_index,
                       __bf16* __restrict__ qw_bf, __bf16* __restrict__ kvw_bf,
                       __bf16* __restrict__ pw_bf, float* __restrict__ bias_pad) {
  int i = blockIdx.x * 256 + threadIdx.x;
  if (i < DIM*DIM)   qw_bf[i] = (__bf16)qw[i];
  if (i < 2*DIM*DIM) kvw_bf[i] = (__bf16)kvw[i];
  if (i < DIM*DIM)   pw_bf[i] = (__bf16)pw[i];
  if (i < HEADS*64*64) {
    int h = i >> 12, rem = i & 4095, q = rem >> 6, k = rem & 63;
    float v;
    if (k >= NTOK)      v = -1e30f;   // key padding: masks softmax for free
    else if (q >= NTOK) v = 0.0f;     // query padding rows are discarded
    else v = rel_table[rel_index[q*NTOK + k] * HEADS + h];
    bias_pad[i] = v;
  }
}

// ============ fully-fused kernel: one block = one window (49 tok) ============
// 512 threads / 8 waves. Two half-passes over heads (6 each):
//   Q-half GEMM -> QB(LDS), KV-half GEMM -> KB + VT(LDS), attention -> AO(LDS);
// then proj GEMM from AO -> out (f32, HBM). Weights stream from L2 per block.
// All LDS tiles XOR-swizzled within 8-chunk groups (<=2-way bank aliasing).
__global__ __launch_bounds__(512, 2) void k_fused(
    const float* __restrict__ x, const float* __restrict__ y,
    const __bf16* __restrict__ qw_bf, const __bf16* __restrict__ kvw_bf,
    const __bf16* __restrict__ pw_bf,
    const float* __restrict__ q_b, const float* __restrict__ kv_b,
    const float* __restrict__ pb, const float* __restrict__ bias_pad,
    float* __restrict__ out)
{
  __shared__ __align__(16) char LDS[147456];   // 144 KB
  char* AST = LDS;             // 2 x 4096 : x/y K-slice dbuf (64 rows x 32 bf16)
  char* QB  = LDS + 8192;      // [64 tok][192 d]  swz
  char* KB  = LDS + 32768;     // [64 tok][192 d]  swz
  char* VTB = LDS + 57344;     // [192 d][64 tok]  swz
  char* AOB = LDS + 81920;     // [64 tok][384 d]  swz
  char* PB  = LDS + 131072;    // 8 waves x [16 q][64 k] swz

  const int win = blockIdx.x;
  const int t = threadIdx.x, lane = t & 63, wave = t >> 6;
  const int l15 = lane & 15, g = lane >> 4;
  const int mh = wave >> 2, q4 = wave & 3;
  const size_t base = (size_t)win * NTOK;

  // staging geometry: thread t loads one float4 of row srow, chunk c8
  const int srow = t >> 3, c8 = t & 7;
  size_t grow = base + srow; if (grow > (size_t)(MTOT-1)) grow = MTOT-1;
  const float* xs = x + grow*DIM + c8*4;
  const float* ys = y + grow*DIM + c8*4;
  const unsigned stw = (unsigned)srow*64 + ((((c8>>1) ^ ((srow>>1)&3))<<4) + (c8&1)*8);
  const unsigned lslot = (unsigned)l15*64 + ((unsigned)(g ^ ((l15>>1)&3)) << 4);
  const float scale = 0.17677669529663687f;   // 32^-0.5

  for (int p = 0; p < 2; ++p) {
    // ---------- Q-half GEMM: QB[64][192] = x @ qw[192p..+192]^T + q_b ----------
    {
      f32x4 acc[2][3];
      #pragma unroll
      for (int a=0;a<2;a++)
        #pragma unroll
        for (int j=0;j<3;j++) acc[a][j] = (f32x4){0.f,0.f,0.f,0.f};
      const __bf16* bptr[3];
      #pragma unroll
      for (int j=0;j<3;j++)
        bptr[j] = qw_bf + (size_t)(192*p + 16*(q4+4*j) + l15)*DIM + g*8;

      float4 s0 = *(const float4*)xs;
      bf16x8 bc0 = *(const bf16x8*)(bptr[0]);
      bf16x8 bc1 = *(const bf16x8*)(bptr[1]);
      bf16x8 bc2 = *(const bf16x8*)(bptr[2]);
      *(bf16x4*)(AST + stw) = cvt4(s0);
      __syncthreads();

      #pragma unroll
      for (int kt = 0; kt < 12; ++kt) {
        const int cb = kt & 1;
        float4 sn; bf16x8 bn0, bn1, bn2;
        if (kt < 11) {
          sn  = *(const float4*)(xs + (kt+1)*32);
          bn0 = *(const bf16x8*)(bptr[0] + (kt+1)*32);
          bn1 = *(const bf16x8*)(bptr[1] + (kt+1)*32);
          bn2 = *(const bf16x8*)(bptr[2] + (kt+1)*32);
        }
        bf16x8 af[2];
        #pragma unroll
        for (int a=0;a<2;a++)
          af[a] = *(const bf16x8*)(AST + cb*4096 + (32*mh + 16*a)*64 + lslot);
        #pragma unroll
        for (int a=0;a<2;a++) {
          acc[a][0] = mfma16(af[a], bc0, acc[a][0]);
          acc[a][1] = mfma16(af[a], bc1, acc[a][1]);
          acc[a][2] = mfma16(af[a], bc2, acc[a][2]);
        }
        if (kt < 11) *(bf16x4*)(AST + (cb^1)*4096 + stw) = cvt4(sn);
        __syncthreads();
        bc0 = bn0; bc1 = bn1; bc2 = bn2;
      }
      #pragma unroll
      for (int j=0;j<3;j++) {
        const int c = 16*(q4+4*j) + l15;          // 0..191
        const float bi = q_b[192*p + c];
        #pragma unroll
        for (int a=0;a<2;a++)
          #pragma unroll
          for (int r=0;r<4;r++) {
            const int tok = 32*mh + 16*a + 4*g + r;
            const unsigned by = (unsigned)tok*384
                + ((((unsigned)(c>>3) ^ (unsigned)(tok&7))<<4) + (c&7)*2);
            *(__bf16*)(QB + by) = (__bf16)(acc[a][j][r] + bi);
          }
      }
    }
    // ---------- KV-half GEMM: KB[64][192], VTB[192][64] ----------
    {
      f32x4 acc[2][6];
      #pragma unroll
      for (int a=0;a<2;a++)
        #pragma unroll
        for (int j=0;j<6;j++) acc[a][j] = (f32x4){0.f,0.f,0.f,0.f};
      const __bf16* bptr[6];
      #pragma unroll
      for (int j=0;j<6;j++) {
        const int c = 16*(q4+4*j) + l15;          // 0..383
        const int row = (j < 3) ? (192*p + c) : (384 + 192*p + (c - 192));
        bptr[j] = kvw_bf + (size_t)row*DIM + g*8;
      }
      float4 s0 = *(const float4*)ys;
      bf16x8 bc[6];
      #pragma unroll
      for (int j=0;j<6;j++) bc[j] = *(const bf16x8*)(bptr[j]);
      *(bf16x4*)(AST + stw) = cvt4(s0);
      __syncthreads();

      #pragma unroll
      for (int kt = 0; kt < 12; ++kt) {
        const int cb = kt & 1;
        float4 sn; bf16x8 bn[6];
        if (kt < 11) {
          sn = *(const float4*)(ys + (kt+1)*32);
          #pragma unroll
          for (int j=0;j<6;j++) bn[j] = *(const bf16x8*)(bptr[j] + (kt+1)*32);
        }
        bf16x8 af[2];
        #pragma unroll
        for (int a=0;a<2;a++)
          af[a] = *(const bf16x8*)(AST + cb*4096 + (32*mh + 16*a)*64 + lslot);
        #pragma unroll
        for (int a=0;a<2;a++)
          #pragma unroll
          for (int j=0;j<6;j++)
            acc[a][j] = mfma16(af[a], bc[j], acc[a][j]);
        if (kt < 11) *(bf16x4*)(AST + (cb^1)*4096 + stw) = cvt4(sn);
        __syncthreads();
        #pragma unroll
        for (int j=0;j<6;j++) bc[j] = bn[j];
      }
      #pragma unroll
      for (int j=0;j<6;j++) {
        const int c = 16*(q4+4*j) + l15;
        if (j < 3) {                                // K part
          const float bi = kv_b[192*p + c];
          #pragma unroll
          for (int a=0;a<2;a++)
            #pragma unroll
            for (int r=0;r<4;r++) {
              const int tok = 32*mh + 16*a + 4*g + r;
              const unsigned by = (unsigned)tok*384
                  + ((((unsigned)(c>>3) ^ (unsigned)(tok&7))<<4) + (c&7)*2);
              *(__bf16*)(KB + by) = (__bf16)(acc[a][j][r] + bi);
            }
        } else {                                    // V part -> transposed store
          const int d = c - 192;                    // 0..191
          const float bi = kv_b[384 + 192*p + d];
          #pragma unroll
          for (int a=0;a<2;a++)
            #pragma unroll
            for (int r=0;r<4;r++) {
              const int tok = 32*mh + 16*a + 4*g + r;
              const unsigned by = (unsigned)d*128
                  + ((((unsigned)(tok>>3) ^ (unsigned)(d&7))<<4) + (tok&7)*2);
              *(__bf16*)(VTB + by) = (__bf16)(acc[a][j][r] + bi);
            }
        }
      }
      __syncthreads();   // QB/KB/VTB visible to all waves
    }
    // ---------- attention-half: 24 tasks (4 row-quarters x 6 heads) ----------
    char* Pw = PB + wave*2048;
    #pragma unroll
    for (int j = 0; j < 3; ++j) {
      const int T = wave + 8*j;
      const int rq = T / 6, hloc = T - rq*6;
      const bf16x8 aq = *(const bf16x8*)(QB + (unsigned)(16*rq + l15)*384
                          + (((unsigned)(hloc*4 + g) ^ (unsigned)(l15&7))<<4));
      f32x4 sacc[4];
      #pragma unroll
      for (int nt=0;nt<4;nt++) {
        const bf16x8 kf = *(const bf16x8*)(KB + (unsigned)(16*nt + l15)*384
                          + (((unsigned)(hloc*4 + g) ^ (unsigned)(l15&7))<<4));
        sacc[nt] = mfma16(aq, kf, (f32x4){0.f,0.f,0.f,0.f});
      }
      const float* bt = bias_pad + (6*p + hloc)*4096;
      float rs[4];
      #pragma unroll
      for (int r=0;r<4;r++) {
        const int q = 16*rq + 4*g + r;
        float v0 = sacc[0][r]*scale + bt[q*64 +  0 + l15];
        float v1 = sacc[1][r]*scale + bt[q*64 + 16 + l15];
        float v2 = sacc[2][r]*scale + bt[q*64 + 32 + l15];
        float v3 = sacc[3][r]*scale + bt[q*64 + 48 + l15];
        float m = fmaxf(fmaxf(v0,v1), fmaxf(v2,v3));
        #pragma unroll
        for (int off=1; off<16; off<<=1) m = fmaxf(m, __shfl_xor(m, off));
        v0 = __expf(v0-m); v1 = __expf(v1-m); v2 = __expf(v2-m); v3 = __expf(v3-m);
        float s = v0+v1+v2+v3;
        #pragma unroll
        for (int off=1; off<16; off<<=1) s += __shfl_xor(s, off);
        rs[r] = s;
        const int qloc = 4*g + r;
        #pragma unroll
        for (int nt=0;nt<4;nt++) {
          const int k = 16*nt + l15;
          const float vv = (nt==0)?v0:(nt==1)?v1:(nt==2)?v2:v3;
          const unsigned pby = (unsigned)qloc*128
              + ((((unsigned)(k>>3) ^ (unsigned)(qloc&7))<<4) + (k&7)*2);
          *(__bf16*)(Pw + pby) = (__bf16)vv;
        }
      }
      #pragma unroll
      for (int dt=0;dt<2;dt++) {
        f32x4 o = (f32x4){0.f,0.f,0.f,0.f};
        #pragma unroll
        for (int ks=0;ks<2;ks++) {
          const bf16x8 pa = *(const bf16x8*)(Pw + (unsigned)l15*128
              + (((unsigned)(4*ks + g) ^ (unsigned)(l15&7))<<4));
          const int d = hloc*32 + 16*dt + l15;
          const bf16x8 vb = *(const bf16x8*)(VTB + (unsigned)d*128
              + (((unsigned)(4*ks + g) ^ (unsigned)(d&7))<<4));
          o = mfma16(pa, vb, o);
        }
        #pragma unroll
        for (int r=0;r<4;r++) {
          const int tok = 16*rq + 4*g + r;
          const int dg = (6*p + hloc)*32 + 16*dt + l15;
          const unsigned by = (unsigned)tok*768
              + ((((unsigned)(dg>>3) ^ (unsigned)(tok&7))<<4) + (dg&7)*2);
          *(__bf16*)(AOB + by) = (__bf16)(o[r] / rs[r]);
        }
      }
    }
    __syncthreads();   // half done: AO partial written; QB/KB/VTB reusable
  }

  // ---------- proj: out = AO @ pw^T + pb (from LDS, no barriers) ----------
  {
    f32x4 acc[2][6];
    #pragma unroll
    for (int a=0;a<2;a++)
      #pragma unroll
      for (int j=0;j<6;j++) acc[a][j] = (f32x4){0.f,0.f,0.f,0.f};
    const __bf16* bptr[6];
    #pragma unroll
    for (int j=0;j<6;j++)
      bptr[j] = pw_bf + (size_t)(16*(q4+4*j) + l15)*DIM + g*8;
    bf16x8 bc[6];
    #pragma unroll
    for (int j=0;j<6;j++) bc[j] = *(const bf16x8*)(bptr[j]);

    #pragma unroll
    for (int kt = 0; kt < 12; ++kt) {
      bf16x8 bn[6];
      if (kt < 11) {
        #pragma unroll
        for (int j=0;j<6;j++) bn[j] = *(const bf16x8*)(bptr[j] + (kt+1)*32);
      }
      bf16x8 af[2];
      #pragma unroll
      for (int a=0;a<2;a++) {
        const int tok = 32*mh + 16*a + l15;
        af[a] = *(const bf16x8*)(AOB + (unsigned)tok*768
                 + (((unsigned)(4*kt + g) ^ (unsigned)(l15&7))<<4));
      }
      #pragma unroll
      for (int a=0;a<2;a++)
        #pragma unroll
        for (int j=0;j<6;j++)
          acc[a][j] = mfma16(af[a], bc[j], acc[a][j]);
      #pragma unroll
      for (int j=0;j<6;j++) bc[j] = bn[j];
    }
    #pragma unroll
    for (int j=0;j<6;j++) {
      const int col = 16*(q4+4*j) + l15;
      const float bi = pb[col];
      #pragma unroll
      for (int a=0;a<2;a++)
        #pragma unroll
        for (int r=0;r<4;r++) {
          const int tok = 32*mh + 16*a + 4*g + r;
          if (tok < NTOK)
            out[(base + tok)*DIM + col] = acc[a][j][r] + bi;
        }
    }
  }
}

extern "C" void kernel_launch(void* const* d_in, const int* in_sizes, int n_in,
                              void* d_out, int out_size, void* d_ws, size_t ws_size,
                              hipStream_t stream)
{
  const float* x   = (const float*)d_in[0];
  const float* y   = (const float*)d_in[1];
  const float* qw  = (const float*)d_in[2];
  const float* qb  = (const float*)d_in[3];
  const float* kvw = (const float*)d_in[4];
  const float* kvb = (const float*)d_in[5];
  const float* pw  = (const float*)d_in[6];
  const float* pb  = (const float*)d_in[7];
  const float* rt  = (const float*)d_in[8];
  const int*   ri  = (const int*)d_in[9];
  float* out = (float*)d_out;

  char* ws = (char*)d_ws;
  const size_t WS_NEEDED = 1376256ull;
  if (ws_size < WS_NEEDED) return;

  __bf16* qw_bf    = (__bf16*)(ws);
  __bf16* kvw_bf   = (__bf16*)(ws + 294912);
  __bf16* pw_bf    = (__bf16*)(ws + 884736);
  float*  bias_pad = (float*)(ws + 1179648);

  k_prep <<<dim3(1152), dim3(256), 0, stream>>>(qw, kvw, pw, rt, ri,
                                                qw_bf, kvw_bf, pw_bf, bias_pad);
  k_fused<<<dim3(NWIN), dim3(512), 0, stream>>>(x, y, qw_bf, kvw_bf, pw_bf,
                                                qb, kvb, pb, bias_pad, out);
}

// Round 10
// 851.110 us; speedup vs baseline: 1.9044x; 1.9044x over previous
//
#include <hip/hip_runtime.h>

#define DIM 384
#define HEADS 12
#define HD 32
#define NTOK 49
#define NWIN 4096
#define MTOT (NWIN*NTOK)   // 200704 = 1568 * 128
#define PSTR 72            // padded LDS row stride (elements) for P and V^T
#define ASTR 392           // AOB row stride (elements): 384 + 8 pad

typedef __attribute__((ext_vector_type(8))) __bf16 bf16x8;
typedef __attribute__((ext_vector_type(4))) __bf16 bf16x4;
typedef __attribute__((ext_vector_type(4))) float f32x4;

static __device__ __forceinline__ f32x4 mfma16(bf16x8 a, bf16x8 b, f32x4 c) {
  return __builtin_amdgcn_mfma_f32_16x16x32_bf16(a, b, c, 0, 0, 0);
}

// async global->LDS, 16B per lane: dest = lds_base(wave-uniform) + lane*16
static __device__ __forceinline__ void gload_lds16(const void* g, void* l) {
  __builtin_amdgcn_global_load_lds(
      (const __attribute__((address_space(1))) unsigned int*)g,
      (__attribute__((address_space(3))) unsigned int*)l, 16, 0, 0);
}

static __device__ __forceinline__ bf16x4 cvt4(float4 v) {
  bf16x4 t;
  t[0]=(__bf16)v.x; t[1]=(__bf16)v.y; t[2]=(__bf16)v.z; t[3]=(__bf16)v.w;
  return t;
}

// ---------------- prep: weights -> bf16, bias table expand ----------------
__global__ void k_prep(const float* __restrict__ qw, const float* __restrict__ kvw,
                       const float* __restrict__ pw, const float* __restrict__ rel_table,
                       const int* __restrict__ rel_index,
                       __bf16* __restrict__ qw_bf, __bf16* __restrict__ kvw_bf,
                       __bf16* __restrict__ pw_bf, float* __restrict__ bias_pad) {
  int i = blockIdx.x * 256 + threadIdx.x;
  if (i < DIM*DIM)   qw_bf[i] = (__bf16)qw[i];
  if (i < 2*DIM*DIM) kvw_bf[i] = (__bf16)kvw[i];
  if (i < DIM*DIM)   pw_bf[i] = (__bf16)pw[i];
  if (i < HEADS*64*64) {
    int h = i >> 12, rem = i & 4095, q = rem >> 6, k = rem & 63;
    float v;
    if (k >= NTOK)      v = -1e30f;   // key padding: masks softmax for free
    else if (q >= NTOK) v = 0.0f;     // query padding rows are discarded
    else v = rel_table[rel_index[q*NTOK + k] * HEADS + h];
    bias_pad[i] = v;
  }
}

// ---------------- fused QKV GEMM (round-6 version, unchanged) ----------------
__global__ __launch_bounds__(256, 4) void k_qkv(
    const float* __restrict__ x, const float* __restrict__ y,
    const __bf16* __restrict__ qw_bf, const __bf16* __restrict__ kvw_bf,
    const float* __restrict__ q_b, const float* __restrict__ kv_b,
    __bf16* __restrict__ Qws, __bf16* __restrict__ Kws, __bf16* __restrict__ Vws)
{
  // 14112 = 8 * 1764 : bijective XCD swizzle
  int b = blockIdx.x;
  int orig = (b & 7) * 1764 + (b >> 3);
  int mtile = orig / 9;
  int nt9 = orig - mtile*9;
  const float* A; const __bf16* Bw; const float* bias; __bf16* Cout;
  int wrow0, col0;
  if (nt9 < 3) { A = x; Bw = qw_bf; bias = q_b; Cout = Qws; wrow0 = nt9*128; col0 = wrow0; }
  else {
    A = y; Bw = kvw_bf; bias = kv_b; wrow0 = (nt9-3)*128;
    if (wrow0 < DIM) { Cout = Kws; col0 = wrow0; } else { Cout = Vws; col0 = wrow0 - DIM; }
  }
  bias += wrow0;

  __shared__ __align__(16) __bf16 As[2*128*32];   // 2 x 8 KB (double buffer)
  __shared__ __align__(16) __bf16 Bs[3*128*32];   // 3 x 8 KB (ring, 2-deep prefetch)

  int t = threadIdx.x, lane = t & 63, wave = t >> 6;
  int l15 = lane & 15, g = lane >> 4;
  int wr = (wave >> 1) * 64, wc = (wave & 1) * 64;
  int row0b = mtile*128;

  int c8 = lane & 7;
  int r8 = lane >> 3;
  int swk = (lane >> 4) & 3;
  const float* asrc = A + (size_t)(row0b + wave*32 + r8)*DIM + c8*4;
  unsigned lwb = (unsigned)wave*2048 + (unsigned)r8*64
               + ((((c8 >> 1) ^ swk) << 4) + (c8 & 1)*8);

  int sr  = 2*(lane >> 3) + ((lane >> 2) & 1);
  int scb = (lane & 3) ^ ((lane >> 3) & 3);
  const __bf16* bsrc0 = Bw + (size_t)(wrow0 + (wave*2    )*16 + sr)*DIM + scb*8;
  const __bf16* bsrc1 = Bw + (size_t)(wrow0 + (wave*2 + 1)*16 + sr)*DIM + scb*8;

  f32x4 acc[4][4];
  #pragma unroll
  for (int a=0;a<4;a++)
    #pragma unroll
    for (int bb=0;bb<4;bb++) acc[a][bb] = (f32x4){0.f,0.f,0.f,0.f};

  {
    float4 s0 = *(const float4*)(asrc);
    float4 s1 = *(const float4*)(asrc +  8*DIM);
    float4 s2 = *(const float4*)(asrc + 16*DIM);
    float4 s3 = *(const float4*)(asrc + 24*DIM);
    gload_lds16(bsrc0,      (char*)Bs +        (wave*2  )*1024);
    gload_lds16(bsrc1,      (char*)Bs +        (wave*2+1)*1024);
    gload_lds16(bsrc0 + 32, (char*)Bs + 8192 + (wave*2  )*1024);
    gload_lds16(bsrc1 + 32, (char*)Bs + 8192 + (wave*2+1)*1024);
    *(bf16x4*)((char*)As + lwb +    0) = cvt4(s0);
    *(bf16x4*)((char*)As + lwb +  512) = cvt4(s1);
    *(bf16x4*)((char*)As + lwb + 1024) = cvt4(s2);
    *(bf16x4*)((char*)As + lwb + 1536) = cvt4(s3);
    asm volatile("s_waitcnt vmcnt(2)" ::: "memory");
    asm volatile("s_waitcnt lgkmcnt(0)" ::: "memory");
    __builtin_amdgcn_s_barrier();
  }

  int lslot = l15*64 + ((g ^ ((l15 >> 1) & 3)) << 4);

  #pragma unroll
  for (int kt = 0; kt < 12; ++kt) {
    const int cur2 = kt & 1, nxt2 = cur2 ^ 1;
    const int cur3 = kt % 3, pre3 = (kt + 2) % 3;
    float4 s0, s1, s2, s3;
    if (kt < 11) {
      int kk = (kt + 1) * 32;
      s0 = *(const float4*)(asrc + kk);
      s1 = *(const float4*)(asrc + kk +  8*DIM);
      s2 = *(const float4*)(asrc + kk + 16*DIM);
      s3 = *(const float4*)(asrc + kk + 24*DIM);
    }
    if (kt < 10) {
      int kk = (kt + 2) * 32;
      gload_lds16(bsrc0 + kk, (char*)Bs + pre3*8192 + (wave*2  )*1024);
      gload_lds16(bsrc1 + kk, (char*)Bs + pre3*8192 + (wave*2+1)*1024);
    }
    bf16x8 af[4], bfv[4];
    #pragma unroll
    for (int a=0;a<4;a++)
      af[a]  = *(const bf16x8*)((const char*)As + cur2*8192 + (wr + a*16)*64 + lslot);
    #pragma unroll
    for (int bb=0;bb<4;bb++)
      bfv[bb] = *(const bf16x8*)((const char*)Bs + cur3*8192 + (wc + bb*16)*64 + lslot);
    #pragma unroll
    for (int a=0;a<4;a++)
      #pragma unroll
      for (int bb=0;bb<4;bb++)
        acc[a][bb] = mfma16(af[a], bfv[bb], acc[a][bb]);
    if (kt < 11) {
      *(bf16x4*)((char*)As + nxt2*8192 + lwb +    0) = cvt4(s0);
      *(bf16x4*)((char*)As + nxt2*8192 + lwb +  512) = cvt4(s1);
      *(bf16x4*)((char*)As + nxt2*8192 + lwb + 1024) = cvt4(s2);
      *(bf16x4*)((char*)As + nxt2*8192 + lwb + 1536) = cvt4(s3);
      if (kt < 10) asm volatile("s_waitcnt vmcnt(2)" ::: "memory");
      else         asm volatile("s_waitcnt vmcnt(0)" ::: "memory");
      asm volatile("s_waitcnt lgkmcnt(0)" ::: "memory");
      __builtin_amdgcn_s_barrier();
    }
  }

  #pragma unroll
  for (int a=0;a<4;a++) {
    #pragma unroll
    for (int bb=0;bb<4;bb++) {
      int colw = wc + bb*16 + l15;
      float bi = bias[colw];
      size_t cbase = (size_t)(row0b + wr + a*16 + 4*g)*DIM + (col0 + colw);
      #pragma unroll
      for (int r=0;r<4;r++)
        Cout[cbase + (size_t)r*DIM] = (__bf16)(acc[a][bb][r] + bi);
    }
  }
}

// ---------- fused attention + projection: AO stays in LDS ----------
// Block = 1 window, 4 waves. Attn phase = round-6 k_attn with P shrunk to
// per-16-row chunks and AO written to LDS (padded stride 392, bank-even).
// Proj phase: out[64x384] = AO @ pw^T + pb; wave = 64 rows x 96 cols;
// B streamed from L2 (full-line reads), 1-step reg prefetch; A from LDS.
__global__ __launch_bounds__(256, 2) void k_attnproj(
    const __bf16* __restrict__ Qws, const __bf16* __restrict__ Kws,
    const __bf16* __restrict__ Vws, const float* __restrict__ bias_pad,
    const __bf16* __restrict__ pw_bf, const float* __restrict__ pb,
    float* __restrict__ out)
{
  __shared__ __align__(16) __bf16 VTsh[4][32*PSTR];   // 18432 B
  __shared__ __align__(16) __bf16 Psh[4][16*PSTR];    //  9216 B
  __shared__ __align__(16) __bf16 AOB[64*ASTR];       // 50176 B  (total 76 KB)
  int b = blockIdx.x;
  int lane = threadIdx.x & 63, wave = threadIdx.x >> 6;
  int l15 = lane & 15, g = lane >> 4;
  __bf16* Pw  = Psh[wave];
  __bf16* VTw = VTsh[wave];
  size_t rowbase = (size_t)b * NTOK * DIM;
  const float scale = 0.17677669529663687f;  // 32^-0.5

  // zero V^T pad columns k in [49,64)
  for (int e = lane; e < 32*15; e += 64) {
    int d = e / 15, k = 49 + (e - d*15);
    VTw[d*PSTR + k] = (__bf16)0.0f;
  }

  for (int hh = 0; hh < 3; hh++) {
    int h = wave + hh*4;
    for (int e = lane; e < NTOK*HD; e += 64) {
      int k = e >> 5, d = e & 31;
      VTw[d*PSTR + k] = Vws[rowbase + (size_t)k*DIM + h*HD + d];
    }
    bf16x8 qf[4], kf[4];
    #pragma unroll
    for (int mt=0; mt<4; mt++) {
      int q = 16*mt + l15; if (q > 48) q = 48;
      qf[mt] = *(const bf16x8*)(Qws + rowbase + (size_t)q*DIM + h*HD + g*8);
    }
    #pragma unroll
    for (int nt=0; nt<4; nt++) {
      int kk = 16*nt + l15; if (kk > 48) kk = 48;
      kf[nt] = *(const bf16x8*)(Kws + rowbase + (size_t)kk*DIM + h*HD + g*8);
    }
    f32x4 sacc[4][4];
    #pragma unroll
    for (int mt=0; mt<4; mt++)
      #pragma unroll
      for (int nt=0; nt<4; nt++)
        sacc[mt][nt] = mfma16(qf[mt], kf[nt], (f32x4){0.f,0.f,0.f,0.f});

    const float* bt = bias_pad + h*4096;
    #pragma unroll
    for (int mt=0; mt<4; mt++) {
      float rs[4];
      #pragma unroll
      for (int r=0; r<4; r++) {
        int q = 16*mt + 4*g + r;
        int qloc = 4*g + r;
        float v0 = sacc[mt][0][r]*scale + bt[q*64 +  0 + l15];
        float v1 = sacc[mt][1][r]*scale + bt[q*64 + 16 + l15];
        float v2 = sacc[mt][2][r]*scale + bt[q*64 + 32 + l15];
        float v3 = sacc[mt][3][r]*scale + bt[q*64 + 48 + l15];
        float m = fmaxf(fmaxf(v0,v1), fmaxf(v2,v3));
        #pragma unroll
        for (int off=1; off<16; off<<=1) m = fmaxf(m, __shfl_xor(m, off));
        v0 = __expf(v0-m); v1 = __expf(v1-m); v2 = __expf(v2-m); v3 = __expf(v3-m);
        float s = v0+v1+v2+v3;
        #pragma unroll
        for (int off=1; off<16; off<<=1) s += __shfl_xor(s, off);
        rs[r] = s;
        Pw[qloc*PSTR +  0 + l15] = (__bf16)v0;
        Pw[qloc*PSTR + 16 + l15] = (__bf16)v1;
        Pw[qloc*PSTR + 32 + l15] = (__bf16)v2;
        Pw[qloc*PSTR + 48 + l15] = (__bf16)v3;
      }
      // PV for this 16-row chunk (wave-local; compiler orders via lgkmcnt)
      #pragma unroll
      for (int dt=0; dt<2; dt++) {
        f32x4 o = (f32x4){0.f,0.f,0.f,0.f};
        #pragma unroll
        for (int ks=0; ks<2; ks++) {
          bf16x8 pa = *(const bf16x8*)(Pw  + l15*PSTR + 32*ks + 8*g);
          bf16x8 vb = *(const bf16x8*)(VTw + (16*dt + l15)*PSTR + 32*ks + 8*g);
          o = mfma16(pa, vb, o);
        }
        #pragma unroll
        for (int r=0; r<4; r++) {
          int tok = 16*mt + 4*g + r;
          AOB[(unsigned)tok*ASTR + h*HD + 16*dt + l15] = (__bf16)(o[r] / rs[r]);
        }
      }
    }
  }
  __syncthreads();   // AO complete (all waves, all heads)

  // ---------- proj phase: wave covers cols [96*wave, 96*wave+96) ----------
  {
    f32x4 acc[4][6];
    #pragma unroll
    for (int a=0;a<4;a++)
      #pragma unroll
      for (int j=0;j<6;j++) acc[a][j] = (f32x4){0.f,0.f,0.f,0.f};
    const __bf16* bptr[6];
    #pragma unroll
    for (int j=0;j<6;j++)
      bptr[j] = pw_bf + (size_t)(96*wave + 16*j + l15)*DIM + g*8;
    bf16x8 bc[6];
    #pragma unroll
    for (int j=0;j<6;j++) bc[j] = *(const bf16x8*)(bptr[j]);

    #pragma unroll
    for (int kt = 0; kt < 12; ++kt) {
      bf16x8 bn[6];
      if (kt < 11) {
        #pragma unroll
        for (int j=0;j<6;j++) bn[j] = *(const bf16x8*)(bptr[j] + (kt+1)*32);
      }
      bf16x8 af[4];
      #pragma unroll
      for (int a=0;a<4;a++)
        af[a] = *(const bf16x8*)(AOB + (unsigned)(16*a + l15)*ASTR + kt*32 + g*8);
      #pragma unroll
      for (int a=0;a<4;a++)
        #pragma unroll
        for (int j=0;j<6;j++)
          acc[a][j] = mfma16(af[a], bc[j], acc[a][j]);
      #pragma unroll
      for (int j=0;j<6;j++) bc[j] = bn[j];
    }
    #pragma unroll
    for (int j=0;j<6;j++) {
      const int col = 96*wave + 16*j + l15;
      const float bi = pb[col];
      #pragma unroll
      for (int a=0;a<4;a++)
        #pragma unroll
        for (int r=0;r<4;r++) {
          const int tok = 16*a + 4*g + r;
          if (tok < NTOK)
            out[((size_t)b*NTOK + tok)*DIM + col] = acc[a][j][r] + bi;
        }
    }
  }
}

extern "C" void kernel_launch(void* const* d_in, const int* in_sizes, int n_in,
                              void* d_out, int out_size, void* d_ws, size_t ws_size,
                              hipStream_t stream)
{
  const float* x   = (const float*)d_in[0];
  const float* y   = (const float*)d_in[1];
  const float* qw  = (const float*)d_in[2];
  const float* qb  = (const float*)d_in[3];
  const float* kvw = (const float*)d_in[4];
  const float* kvb = (const float*)d_in[5];
  const float* pw  = (const float*)d_in[6];
  const float* pb  = (const float*)d_in[7];
  const float* rt  = (const float*)d_in[8];
  const int*   ri  = (const int*)d_in[9];
  float* out = (float*)d_out;

  char* ws = (char*)d_ws;
  const size_t WS_NEEDED = 1376256ull + 3ull*154140672ull;
  if (ws_size < WS_NEEDED) return;

  __bf16* qw_bf    = (__bf16*)(ws);
  __bf16* kvw_bf   = (__bf16*)(ws + 294912);
  __bf16* pw_bf    = (__bf16*)(ws + 884736);
  float*  bias_pad = (float*)(ws + 1179648);
  __bf16* Qws      = (__bf16*)(ws + 1376256);
  __bf16* Kws      = Qws + (size_t)MTOT*DIM;
  __bf16* Vws      = Kws + (size_t)MTOT*DIM;

  k_prep    <<<dim3(1152), dim3(256), 0, stream>>>(qw, kvw, pw, rt, ri, qw_bf, kvw_bf, pw_bf, bias_pad);
  k_qkv     <<<dim3(1568*9), dim3(256), 0, stream>>>(x, y, qw_bf, kvw_bf, qb, kvb, Qws, Kws, Vws);
  k_attnproj<<<dim3(NWIN), dim3(256), 0, stream>>>(Qws, Kws, Vws, bias_pad, pw_bf, pb, out);
}